// Round 1
// 181.121 us; speedup vs baseline: 1.0647x; 1.0647x over previous
//
#include <hip/hip_runtime.h>

// Problem constants (from reference setup_inputs)
constexpr int Bn  = 256;   // batch
constexpr int Nn  = 16;    // template children
constexpr int Mn  = 128;   // sequence length
constexpr int Vn  = 64;    // vocab
constexpr int Hn  = 128;   // hidden
constexpr int Kn  = 8;     // template rows
constexpr int NP1 = 17;    // N+1
constexpr int KN  = Kn * NP1; // 136

// Block = 512 threads = 8 waves: one wave per template row k in Phase 2.
__global__ __launch_bounds__(512) void fused_template_pack(
    const float* __restrict__ dec,       // [B,N,M,V]
    const float* __restrict__ type_emb,  // [T,H]
    const float* __restrict__ w_sem,     // [15, K*(N+1), H]
    const float* __restrict__ b_sem,     // [15, K*(N+1)]
    const float* __restrict__ gumbel,    // [B,K,N+1]
    const int*   __restrict__ ttypes,    // [B]
    const int*   __restrict__ spans,     // [B]
    float*       __restrict__ out)       // [B,M,V]
{
    const int b    = blockIdx.x;
    const int tid  = threadIdx.x;
    const int lane = tid & 63;
    const int wave = tid >> 6;           // 0..7

    __shared__ float s_scores[KN];
    __shared__ int   s_sel[Kn];
    __shared__ int   s_len[Kn];
    __shared__ int   s_off[Kn];
    __shared__ int   s_eff[Kn];
    __shared__ int   s_total;

    const int t    = ttypes[b];          // block-uniform
    const int span = spans[b];

    // ---- Phase 1: template selection (argmax_n of logits + gumbel) ----
    if (t != 20) {
        if (tid < KN) {
            const int n = tid % NP1;
            float score = -1e30f;
            if (n <= span) {
                const float4* wrow = (const float4*)(w_sem + ((size_t)(t - 9) * KN + tid) * Hn);
                const float4* erow = (const float4*)(type_emb + (size_t)t * Hn);
                float acc = 0.f;
                #pragma unroll
                for (int i = 0; i < Hn / 4; ++i) {
                    float4 wv = wrow[i];
                    float4 ev = erow[i];
                    acc += wv.x * ev.x + wv.y * ev.y + wv.z * ev.z + wv.w * ev.w;
                }
                score = acc + b_sem[(t - 9) * KN + tid] + gumbel[(size_t)b * KN + tid];
            }
            s_scores[tid] = score;
        }
        __syncthreads();
        if (tid < Kn) {
            int best = 0;
            float bv = s_scores[tid * NP1];
            #pragma unroll
            for (int n = 1; n < NP1; ++n) {
                float v = s_scores[tid * NP1 + n];
                if (v > bv) { bv = v; best = n; }   // first-max tie-break (strict >)
            }
            s_sel[tid] = best;
        }
    } else {
        // special start template: row 0 -> child 1, rows 1..7 -> pad
        if (tid < Kn) s_sel[tid] = (tid == 0) ? 1 : 0;
    }
    __syncthreads();

    // ---- Phase 2: per-template effective length, BACKWARD early-exit scan ----
    // len[k] = last m (1-based) with argmax_v dec[b, sel-1, m, :] != 0; 0 for pad.
    // For i.i.d. data P(argmax==0) = 1/V = 1/64, so E[positions scanned] ~= 1.016:
    // reads ~256 B per template instead of the old 32 KB full-row scan.
    // One wave per k; lane j holds dec[..., m, j]; wave argmax with
    // first-index tie-break (matches jnp.argmax).
    if (wave < Kn) {
        const int s = s_sel[wave];
        int len = 0;
        if (s > 0) {
            const float* row = dec + (((size_t)b * Nn + (s - 1)) * Mn) * Vn;
            for (int m = Mn - 1; m >= 0; --m) {
                float bv = row[(size_t)m * Vn + lane];
                int   bi = lane;
                #pragma unroll
                for (int d = 1; d < 64; d <<= 1) {
                    float ov = __shfl_xor(bv, d, 64);
                    int   oi = __shfl_xor(bi, d, 64);
                    if (ov > bv || (ov == bv && oi < bi)) { bv = ov; bi = oi; }
                }
                // bi is uniform across the wave after the butterfly
                if (bi != 0) { len = m + 1; break; }
            }
        }
        if (lane == 0) s_len[wave] = len;
    }
    __syncthreads();

    // ---- Phase 3: sequential packing offsets (scan over K=8) ----
    if (tid == 0) {
        int idx = 0;
        #pragma unroll
        for (int k = 0; k < Kn; ++k) {
            const int eff = min(s_len[k], Mn - idx);
            s_off[k] = idx;
            s_eff[k] = eff;
            idx += eff;
        }
        s_total = idx;
    }
    __syncthreads();

    // ---- Phase 4: copy packed rows ----
    // Statistically only ~1 template has eff > 0 (first non-pad k saturates
    // idx at M=128), so this is ~32 KB read + 32 KB write per block.
    float4* outb = (float4*)(out + (size_t)b * Mn * Vn);
    for (int k = 0; k < Kn; ++k) {
        const int eff = s_eff[k];
        if (eff == 0) continue;
        const float4* src =
            (const float4*)(dec + (((size_t)b * Nn + (s_sel[k] - 1)) * Mn) * Vn);
        float4* dst = outb + (size_t)s_off[k] * (Vn / 4);
        const int cnt = eff * (Vn / 4);
        for (int i = tid; i < cnt; i += 512) dst[i] = src[i];
    }

    // ---- Phase 5: zero-fill the tail rows ----
    const int total = s_total;
    const int zcnt  = (Mn - total) * (Vn / 4);
    float4* zdst = outb + (size_t)total * (Vn / 4);
    const float4 zero = make_float4(0.f, 0.f, 0.f, 0.f);
    for (int i = tid; i < zcnt; i += 512) zdst[i] = zero;
}

extern "C" void kernel_launch(void* const* d_in, const int* in_sizes, int n_in,
                              void* d_out, int out_size, void* d_ws, size_t ws_size,
                              hipStream_t stream) {
    const float* dec      = (const float*)d_in[0];
    const float* type_emb = (const float*)d_in[1];
    const float* w_sem    = (const float*)d_in[2];
    const float* b_sem    = (const float*)d_in[3];
    const float* gumbel   = (const float*)d_in[4];
    const int*   ttypes   = (const int*)d_in[5];
    const int*   spans    = (const int*)d_in[6];
    float* out = (float*)d_out;

    fused_template_pack<<<Bn, 512, 0, stream>>>(
        dec, type_emb, w_sem, b_sem, gumbel, ttypes, spans, out);
}

// Round 2
// 179.237 us; speedup vs baseline: 1.0759x; 1.0105x over previous
//
#include <hip/hip_runtime.h>

// Problem constants (from reference setup_inputs)
constexpr int Bn  = 256;   // batch
constexpr int Nn  = 16;    // template children
constexpr int Mn  = 128;   // sequence length
constexpr int Vn  = 64;    // vocab
constexpr int Hn  = 128;   // hidden
constexpr int Kn  = 8;     // template rows
constexpr int NP1 = 17;    // N+1
constexpr int KN  = Kn * NP1; // 136

// Wave-wide argmax over 64 lanes, first-index tie-break (matches jnp.argmax).
// Returns true iff the winning lane index != 0. Result is wave-uniform.
__device__ __forceinline__ bool wave_argmax_is_nonzero(float v, int lane) {
    float bv = v;
    int   bi = lane;
    #pragma unroll
    for (int d = 1; d < 64; d <<= 1) {
        float ov = __shfl_xor(bv, d, 64);
        int   oi = __shfl_xor(bi, d, 64);
        if (ov > bv || (ov == bv && oi < bi)) { bv = ov; bi = oi; }
    }
    return bi != 0;
}

// Block = 512 threads = 8 waves.
// Waves 0-3: speculative per-child length probes (independent of t/sel).
// Threads 376-511 (waves 5-7 + tail of 5): logits scoring. Runs CONCURRENTLY
// with the probes — collapses the old serial phase chain.
__global__ __launch_bounds__(512) void fused_template_pack(
    const float* __restrict__ dec,       // [B,N,M,V]
    const float* __restrict__ type_emb,  // [T,H]
    const float* __restrict__ w_sem,     // [15, K*(N+1), H]
    const float* __restrict__ b_sem,     // [15, K*(N+1)]
    const float* __restrict__ gumbel,    // [B,K,N+1]
    const int*   __restrict__ ttypes,    // [B]
    const int*   __restrict__ spans,     // [B]
    float*       __restrict__ out)       // [B,M,V]
{
    const int b    = blockIdx.x;
    const int tid  = threadIdx.x;
    const int lane = tid & 63;
    const int wave = tid >> 6;           // 0..7

    __shared__ float s_scores[KN];
    __shared__ int   s_clen[Nn];         // speculative len per child 0..15
    __shared__ int   s_sel[Kn];
    __shared__ int   s_len[Kn];

    const int t    = ttypes[b];          // block-uniform
    const int span = spans[b];

    // ---- Concurrent phase A (waves 0-3): probe effective length of ALL 16
    // children. len(c) = last m (1-based) with argmax_v dec[b,c,m,:] != 0.
    // For i.i.d. data P(argmax==0)=1/64, so the answer is almost always in the
    // last 4 positions: issue those 16 loads upfront (4 children x 4 pos),
    // rare all-pad tail falls back to a serial backward scan.
    if (wave < 4) {
        const float* base = dec + (size_t)b * Nn * Mn * Vn + lane;
        float g[4][4];
        #pragma unroll
        for (int j = 0; j < 4; ++j) {
            const float* row = base + (size_t)(wave * 4 + j) * Mn * Vn;
            #pragma unroll
            for (int p = 0; p < 4; ++p)
                g[j][p] = row[(size_t)(127 - p) * Vn];
        }
        #pragma unroll
        for (int j = 0; j < 4; ++j) {
            int len = 0;
            #pragma unroll
            for (int p = 0; p < 4; ++p) {
                if (len == 0 && wave_argmax_is_nonzero(g[j][p], lane))
                    len = 128 - p;       // 1-based length
            }
            if (len == 0) {              // rare: last 4 positions all pad
                const float* row = base + (size_t)(wave * 4 + j) * Mn * Vn;
                for (int m = Mn - 5; m >= 0; --m) {
                    if (wave_argmax_is_nonzero(row[(size_t)m * Vn], lane)) {
                        len = m + 1;
                        break;
                    }
                }
            }
            if (lane == 0) s_clen[wave * 4 + j] = len;
        }
    }

    // ---- Concurrent phase B (tid 376..511): template logits ----
    if (t != 20 && tid >= 512 - KN) {
        const int j = tid - (512 - KN);  // 0..135 = k*17 + n
        const int n = j % NP1;
        float score = -1e30f;
        if (n <= span) {
            const float4* wrow = (const float4*)(w_sem + ((size_t)(t - 9) * KN + j) * Hn);
            const float4* erow = (const float4*)(type_emb + (size_t)t * Hn);
            float acc = 0.f;
            #pragma unroll
            for (int i = 0; i < Hn / 4; ++i) {
                float4 wv = wrow[i];
                float4 ev = erow[i];
                acc += wv.x * ev.x + wv.y * ev.y + wv.z * ev.z + wv.w * ev.w;
            }
            score = acc + b_sem[(t - 9) * KN + j] + gumbel[(size_t)b * KN + j];
        }
        s_scores[j] = score;
    }
    __syncthreads();

    // ---- Combine: sel[k] = argmax_n score, len[k] = clen[sel-1] ----
    if (tid < Kn) {
        int sel;
        if (t != 20) {
            int best = 0;
            float bv = s_scores[tid * NP1];
            #pragma unroll
            for (int n = 1; n < NP1; ++n) {
                float v = s_scores[tid * NP1 + n];
                if (v > bv) { bv = v; best = n; }   // first-max tie-break
            }
            sel = best;
        } else {
            sel = (tid == 0) ? 1 : 0;   // special start template for type 20
        }
        s_sel[tid] = sel;
        s_len[tid] = (sel > 0) ? s_clen[sel - 1] : 0;
    }
    __syncthreads();

    // ---- Packing scan: computed redundantly per-thread in registers ----
    int off[Kn], eff[Kn], sel_r[Kn];
    int idx = 0;
    #pragma unroll
    for (int k = 0; k < Kn; ++k) {
        sel_r[k] = s_sel[k];
        const int e = min(s_len[k], Mn - idx);
        off[k] = idx;
        eff[k] = e;
        idx += e;
    }

    // ---- Copy packed rows (statistically ~1 template fills all of M) ----
    float4* outb = (float4*)(out + (size_t)b * Mn * Vn);
    #pragma unroll
    for (int k = 0; k < Kn; ++k) {
        if (eff[k] == 0) continue;
        const float4* src =
            (const float4*)(dec + (((size_t)b * Nn + (sel_r[k] - 1)) * Mn) * Vn);
        float4* dst = outb + (size_t)off[k] * (Vn / 4);
        const int cnt = eff[k] * (Vn / 4);
        for (int i = tid; i < cnt; i += 512) dst[i] = src[i];
    }

    // ---- Zero-fill the tail rows (usually zcnt == 0) ----
    const int zcnt = (Mn - idx) * (Vn / 4);
    float4* zdst = outb + (size_t)idx * (Vn / 4);
    const float4 zero = make_float4(0.f, 0.f, 0.f, 0.f);
    for (int i = tid; i < zcnt; i += 512) zdst[i] = zero;
}

extern "C" void kernel_launch(void* const* d_in, const int* in_sizes, int n_in,
                              void* d_out, int out_size, void* d_ws, size_t ws_size,
                              hipStream_t stream) {
    const float* dec      = (const float*)d_in[0];
    const float* type_emb = (const float*)d_in[1];
    const float* w_sem    = (const float*)d_in[2];
    const float* b_sem    = (const float*)d_in[3];
    const float* gumbel   = (const float*)d_in[4];
    const int*   ttypes   = (const int*)d_in[5];
    const int*   spans    = (const int*)d_in[6];
    float* out = (float*)d_out;

    fused_template_pack<<<Bn, 512, 0, stream>>>(
        dec, type_emb, w_sem, b_sem, gumbel, ttypes, spans, out);
}

// Round 3
// 179.085 us; speedup vs baseline: 1.0768x; 1.0008x over previous
//
#include <hip/hip_runtime.h>

// Problem constants (from reference setup_inputs)
constexpr int Bn  = 256;   // batch
constexpr int Nn  = 16;    // template children
constexpr int Mn  = 128;   // sequence length
constexpr int Vn  = 64;    // vocab
constexpr int Hn  = 128;   // hidden
constexpr int Kn  = 8;     // template rows
constexpr int NP1 = 17;    // N+1
constexpr int KN  = Kn * NP1; // 136

// Wave-wide argmax over 64 lanes, first-index tie-break (matches jnp.argmax).
// Returns true iff the winning lane index != 0. Result is wave-uniform.
__device__ __forceinline__ bool wave_argmax_is_nonzero(float v, int lane) {
    float bv = v;
    int   bi = lane;
    #pragma unroll
    for (int d = 1; d < 64; d <<= 1) {
        float ov = __shfl_xor(bv, d, 64);
        int   oi = __shfl_xor(bi, d, 64);
        if (ov > bv || (ov == bv && oi < bi)) { bv = ov; bi = oi; }
    }
    return bi != 0;
}

// Block = 512 threads = 8 waves.
// Waves 0-3: speculative per-child length probes (independent of t/sel).
// Threads 376-511: logits scoring — runs CONCURRENTLY with the probes.
// Output: single register-gather pass, 4 float4 slots/thread, all loads
// issued before any store (32 KB/CU in flight -> HBM latency hidden).
__global__ __launch_bounds__(512) void fused_template_pack(
    const float* __restrict__ dec,       // [B,N,M,V]
    const float* __restrict__ type_emb,  // [T,H]
    const float* __restrict__ w_sem,     // [15, K*(N+1), H]
    const float* __restrict__ b_sem,     // [15, K*(N+1)]
    const float* __restrict__ gumbel,    // [B,K,N+1]
    const int*   __restrict__ ttypes,    // [B]
    const int*   __restrict__ spans,     // [B]
    float*       __restrict__ out)       // [B,M,V]
{
    const int b    = blockIdx.x;
    const int tid  = threadIdx.x;
    const int lane = tid & 63;
    const int wave = tid >> 6;           // 0..7

    __shared__ float s_scores[KN];
    __shared__ int   s_clen[Nn];         // speculative len per child 0..15
    __shared__ int   s_sel[Kn];
    __shared__ int   s_len[Kn];

    const int t    = ttypes[b];          // block-uniform
    const int span = spans[b];

    // ---- Concurrent phase A (waves 0-3): probe effective length of ALL 16
    // children. len(c) = last m (1-based) with argmax_v dec[b,c,m,:] != 0.
    // For i.i.d. data P(argmax==0)=1/64: answer almost always in the last 4
    // positions -> issue those 16 loads upfront; rare all-pad tail falls back
    // to a serial backward scan.
    if (wave < 4) {
        const float* base = dec + (size_t)b * Nn * Mn * Vn + lane;
        float g[4][4];
        #pragma unroll
        for (int j = 0; j < 4; ++j) {
            const float* row = base + (size_t)(wave * 4 + j) * Mn * Vn;
            #pragma unroll
            for (int p = 0; p < 4; ++p)
                g[j][p] = row[(size_t)(127 - p) * Vn];
        }
        #pragma unroll
        for (int j = 0; j < 4; ++j) {
            int len = 0;
            #pragma unroll
            for (int p = 0; p < 4; ++p) {
                if (len == 0 && wave_argmax_is_nonzero(g[j][p], lane))
                    len = 128 - p;       // 1-based length
            }
            if (len == 0) {              // rare: last 4 positions all pad
                const float* row = base + (size_t)(wave * 4 + j) * Mn * Vn;
                for (int m = Mn - 5; m >= 0; --m) {
                    if (wave_argmax_is_nonzero(row[(size_t)m * Vn], lane)) {
                        len = m + 1;
                        break;
                    }
                }
            }
            if (lane == 0) s_clen[wave * 4 + j] = len;
        }
    }

    // ---- Concurrent phase B (tid 376..511): template logits ----
    if (t != 20 && tid >= 512 - KN) {
        const int j = tid - (512 - KN);  // 0..135 = k*17 + n
        const int n = j % NP1;
        float score = -1e30f;
        if (n <= span) {
            const float4* wrow = (const float4*)(w_sem + ((size_t)(t - 9) * KN + j) * Hn);
            const float4* erow = (const float4*)(type_emb + (size_t)t * Hn);
            float acc = 0.f;
            #pragma unroll
            for (int i = 0; i < Hn / 4; ++i) {
                float4 wv = wrow[i];
                float4 ev = erow[i];
                acc += wv.x * ev.x + wv.y * ev.y + wv.z * ev.z + wv.w * ev.w;
            }
            score = acc + b_sem[(t - 9) * KN + j] + gumbel[(size_t)b * KN + j];
        }
        s_scores[j] = score;
    }
    __syncthreads();

    // ---- Combine: sel[k] = argmax_n score, len[k] = clen[sel-1] ----
    if (tid < Kn) {
        int sel;
        if (t != 20) {
            int best = 0;
            float bv = s_scores[tid * NP1];
            #pragma unroll
            for (int n = 1; n < NP1; ++n) {
                float v = s_scores[tid * NP1 + n];
                if (v > bv) { bv = v; best = n; }   // first-max tie-break
            }
            sel = best;
        } else {
            sel = (tid == 0) ? 1 : 0;   // special start template for type 20
        }
        s_sel[tid] = sel;
        s_len[tid] = (sel > 0) ? s_clen[sel - 1] : 0;
    }
    __syncthreads();

    // ---- Packing scan: computed redundantly per-thread in registers ----
    int off[Kn], eff[Kn], sel_r[Kn];
    int idx = 0;
    #pragma unroll
    for (int k = 0; k < Kn; ++k) {
        sel_r[k] = s_sel[k];
        const int e = min(s_len[k], Mn - idx);
        off[k] = idx;
        eff[k] = e;
        idx += e;
    }

    // ---- Output: single register-gather pass (merged copy + zero-fill) ----
    // 2048 output float4s, 4 per thread. For each slot, resolve the source
    // row via an unrolled 8-way interval test, issue all gather loads first
    // (independent, exec-masked), then 4 coalesced stores.
    const float4* decf4 = (const float4*)dec;
    float4*       outb  = (float4*)(out + (size_t)b * Mn * Vn);

    long long si[4];
    #pragma unroll
    for (int i = 0; i < 4; ++i) {
        const int e   = tid + i * 512;   // output float4 index, 0..2047
        const int row = e >> 4;          // output row 0..127
        long long s = -1;
        #pragma unroll
        for (int k = 0; k < Kn; ++k) {
            if (row >= off[k] && row < off[k] + eff[k]) {
                s = ((long long)(b * Nn + sel_r[k] - 1) * Mn + (row - off[k])) * (Vn / 4)
                    + (e & 15);
            }
        }
        si[i] = s;
    }

    float4 r[4];
    #pragma unroll
    for (int i = 0; i < 4; ++i) r[i] = make_float4(0.f, 0.f, 0.f, 0.f);
    #pragma unroll
    for (int i = 0; i < 4; ++i) if (si[i] >= 0) r[i] = decf4[si[i]];
    #pragma unroll
    for (int i = 0; i < 4; ++i) outb[tid + i * 512] = r[i];
}

extern "C" void kernel_launch(void* const* d_in, const int* in_sizes, int n_in,
                              void* d_out, int out_size, void* d_ws, size_t ws_size,
                              hipStream_t stream) {
    const float* dec      = (const float*)d_in[0];
    const float* type_emb = (const float*)d_in[1];
    const float* w_sem    = (const float*)d_in[2];
    const float* b_sem    = (const float*)d_in[3];
    const float* gumbel   = (const float*)d_in[4];
    const int*   ttypes   = (const int*)d_in[5];
    const int*   spans    = (const int*)d_in[6];
    float* out = (float*)d_out;

    fused_template_pack<<<Bn, 512, 0, stream>>>(
        dec, type_emb, w_sem, b_sem, gumbel, ttypes, spans, out);
}